// Round 1
// baseline (7937.635 us; speedup 1.0000x reference)
//
#include <hip/hip_runtime.h>

#define B_ 64
#define T_ 128
#define D_ 1024
#define K2_ 2048
#define G_ 4096

typedef __attribute__((ext_vector_type(8))) short bf16x8;
typedef __attribute__((ext_vector_type(4))) float f32x4;
typedef unsigned short u16;

__device__ __forceinline__ u16 f2bf(float f) {
  unsigned int u = __float_as_uint(f);
  u += 0x7FFF + ((u >> 16) & 1);   // round-to-nearest-even
  return (u16)(u >> 16);
}

// Wt[n][k] = bf16(W[k][n]);  W:[2048][4096] f32, Wt:[4096][2048] bf16
__global__ __launch_bounds__(256) void transpose_w(const float* __restrict__ W,
                                                   u16* __restrict__ Wt) {
  __shared__ u16 tile[64][65];
  int bn = blockIdx.x & 63;   // n-tile 0..63
  int bk = blockIdx.x >> 6;   // k-tile 0..31
  int n0 = bn * 64, k0 = bk * 64;
  for (int i = threadIdx.x; i < 4096; i += 256) {
    int r = i >> 6, c = i & 63;               // r=k_local, c=n_local (coalesced read)
    tile[c][r] = f2bf(W[(size_t)(k0 + r) * G_ + n0 + c]);
  }
  __syncthreads();
  for (int i = threadIdx.x; i < 4096; i += 256) {
    int r = i >> 6, c = i & 63;               // r=n_local, c=k_local (coalesced write)
    Wt[(size_t)(n0 + r) * K2_ + k0 + c] = tile[r][c];
  }
}

// xg[(t*B+b)*D + d] = bf16(emb[inputs[b][t]][d])
__global__ __launch_bounds__(256) void gather_x(const int* __restrict__ inputs,
                                                const float* __restrict__ emb,
                                                u16* __restrict__ xg) {
  int idx = blockIdx.x * 256 + threadIdx.x;   // T*B*D/4 = 2,097,152 exactly
  int d4 = idx & 255;                          // D/4 = 256
  int tb = idx >> 8;
  int t = tb >> 6, b = tb & 63;
  int tok = inputs[b * T_ + t];
  float4 v = ((const float4*)(emb + (size_t)tok * D_))[d4];
  unsigned long long pk = (unsigned long long)f2bf(v.x)
                        | ((unsigned long long)f2bf(v.y) << 16)
                        | ((unsigned long long)f2bf(v.z) << 32)
                        | ((unsigned long long)f2bf(v.w) << 48);
  *(unsigned long long*)(xg + (size_t)tb * D_ + d4 * 4) = pk;
}

__global__ void zero_buf(uint4* p, int n) {
  int i = blockIdx.x * blockDim.x + threadIdx.x;
  if (i < n) p[i] = make_uint4(0u, 0u, 0u, 0u);
}

// One timestep of one layer, fully fused GEMM + LSTM cell.
// grid 128 blocks (8 d-cols each) x 512 threads (8 waves = 4 row-tiles x 2 col-tiles).
// A = [x_t | h]  (64 x 2048 bf16), B = Wt rows (gate-grouped columns), C += bias -> cell.
template<int LAYER>
__global__ __launch_bounds__(512) void lstm_step(
    const u16* __restrict__ xbase,   // xg (L1) or h1n_all (L2), indexed by t
    const u16* __restrict__ wt,      // [4096][2048] bf16
    const float* __restrict__ bias,  // [4096] f32
    float* __restrict__ c,           // [B][D] f32 state
    u16* __restrict__ hb,            // [B][D] bf16 state
    u16* __restrict__ h1n_out,       // L1: h1n_all base; L2: unused
    float* __restrict__ out,         // L2: d_out accumulator; L1: unused
    const int* __restrict__ lengths,
    int t) {
  __shared__ float g_lds[64][33];    // [batch][gate*8 + dcol] gate pre-activations
  const int tid = threadIdx.x;
  const int lane = tid & 63;
  const int wv = tid >> 6;           // 0..7
  const int rt = wv & 3;             // row-tile (16 batch rows)
  const int ct = wv >> 2;            // 0: gates i,j   1: gates f,o
  const int d0 = blockIdx.x * 8;
  const int col = lane & 15;
  const int kb = (lane >> 4) * 8;    // k-offset of this lane's 8 elements

  const int gate = ct * 2 + (col >> 3);
  const int dc = col & 7;
  const int n = gate * D_ + d0 + dc;           // gate-column in [0,4096)
  const u16* wrow = wt + (size_t)n * K2_;
  const float biasv = bias[n];

  const int arow = rt * 16 + col;              // batch row for A-fragment
  const u16* xrow = xbase + ((size_t)t * B_ + arow) * D_ + kb;
  const u16* hrow = hb + (size_t)arow * D_ + kb;

  f32x4 acc = {0.f, 0.f, 0.f, 0.f};

  // K-half 1: x contribution (k in [0,1024))
  #pragma unroll 8
  for (int kk = 0; kk < 32; ++kk) {
    bf16x8 a = *(const bf16x8*)(xrow + kk * 32);
    bf16x8 b = *(const bf16x8*)(wrow + kb + kk * 32);
    acc = __builtin_amdgcn_mfma_f32_16x16x32_bf16(a, b, acc, 0, 0, 0);
  }
  // K-half 2: h contribution (k in [1024,2048))
  #pragma unroll 8
  for (int kk = 0; kk < 32; ++kk) {
    bf16x8 a = *(const bf16x8*)(hrow + kk * 32);
    bf16x8 b = *(const bf16x8*)(wrow + 1024 + kb + kk * 32);
    acc = __builtin_amdgcn_mfma_f32_16x16x32_bf16(a, b, acc, 0, 0, 0);
  }

  // C/D layout (measured, guide m89): col = lane&15, row = (lane>>4)*4 + r
  #pragma unroll
  for (int r = 0; r < 4; ++r) {
    int row = rt * 16 + (lane >> 4) * 4 + r;
    g_lds[row][gate * 8 + dc] = acc[r] + biasv;
  }
  __syncthreads();

  // Cell: 512 threads = 64 rows x 8 dcols
  {
    int row = tid >> 3;
    int d = tid & 7;
    float gi = g_lds[row][d];
    float gj = g_lds[row][8 + d];
    float gf = g_lds[row][16 + d];
    float go = g_lds[row][24 + d];
    float is = 1.f / (1.f + expf(-gi));
    float fs = 1.f / (1.f + expf(-gf));
    float os = 1.f / (1.f + expf(-go));
    float jt = tanhf(gj);
    size_t off = (size_t)row * D_ + d0 + d;
    float c_old = c[off];
    float c_new = c_old * fs + is * jt;
    float h_new = tanhf(c_new) * os;
    bool m = t < lengths[row];
    if (LAYER == 1) {
      // raw (unmasked) h1n feeds layer 2, exactly as the reference
      h1n_out[((size_t)t * B_ + row) * D_ + d0 + d] = f2bf(h_new);
      if (m) { c[off] = c_new; hb[off] = f2bf(h_new); }
    } else {
      if (m) { c[off] = c_new; hb[off] = f2bf(h_new); out[off] += h_new; }
    }
  }
}

extern "C" void kernel_launch(void* const* d_in, const int* in_sizes, int n_in,
                              void* d_out, int out_size, void* d_ws, size_t ws_size,
                              hipStream_t stream) {
  const int* inputs    = (const int*)d_in[0];
  const int* lengths   = (const int*)d_in[1];
  const float* emb     = (const float*)d_in[2];
  const float* W1      = (const float*)d_in[3];
  const float* b1      = (const float*)d_in[4];
  const float* W2      = (const float*)d_in[5];
  const float* b2      = (const float*)d_in[6];
  float* out = (float*)d_out;

  // workspace carve: ~64.8 MiB total
  char* p = (char*)d_ws;
  u16* wt1 = (u16*)p; p += (size_t)G_ * K2_ * 2;      // 16 MiB
  u16* wt2 = (u16*)p; p += (size_t)G_ * K2_ * 2;      // 16 MiB
  u16* xg  = (u16*)p; p += (size_t)T_ * B_ * D_ * 2;  // 16 MiB
  u16* h1n = (u16*)p; p += (size_t)T_ * B_ * D_ * 2;  // 16 MiB
  float* c1 = (float*)p; p += (size_t)B_ * D_ * 4;    // states contiguous: 768 KiB
  float* c2 = (float*)p; p += (size_t)B_ * D_ * 4;
  u16* h1b = (u16*)p; p += (size_t)B_ * D_ * 2;
  u16* h2b = (u16*)p; p += (size_t)B_ * D_ * 2;

  hipLaunchKernelGGL(transpose_w, dim3(2048), dim3(256), 0, stream, W1, wt1);
  hipLaunchKernelGGL(transpose_w, dim3(2048), dim3(256), 0, stream, W2, wt2);
  hipLaunchKernelGGL(gather_x, dim3(8192), dim3(256), 0, stream, inputs, emb, xg);
  // zero c1,c2,h1b,h2b (contiguous 768 KiB = 49152 uint4) and d_out (16384 uint4)
  hipLaunchKernelGGL(zero_buf, dim3(192), dim3(256), 0, stream, (uint4*)c1, 49152);
  hipLaunchKernelGGL(zero_buf, dim3(64), dim3(256), 0, stream, (uint4*)out, 16384);

  for (int t = 0; t < T_; ++t) {
    hipLaunchKernelGGL((lstm_step<1>), dim3(128), dim3(512), 0, stream,
                       xg, wt1, b1, c1, h1b, h1n, (float*)nullptr, lengths, t);
    hipLaunchKernelGGL((lstm_step<2>), dim3(128), dim3(512), 0, stream,
                       h1n, wt2, b2, c2, h2b, (u16*)nullptr, out, lengths, t);
  }
}

// Round 2
// 3333.617 us; speedup vs baseline: 2.3811x; 2.3811x over previous
//
#include <hip/hip_runtime.h>

#define B_ 64
#define T_ 128
#define D_ 1024
#define K2_ 2048
#define G_ 4096

typedef __attribute__((ext_vector_type(8))) short bf16x8;
typedef __attribute__((ext_vector_type(4))) float f32x4;
typedef unsigned short u16;

__device__ __forceinline__ u16 f2bf(float f) {
  unsigned int u = __float_as_uint(f);
  u += 0x7FFF + ((u >> 16) & 1);   // round-to-nearest-even
  return (u16)(u >> 16);
}

// Wt[n][k] = bf16(W[k][n]);  W:[2048][4096] f32, Wt:[4096][2048] bf16
__global__ __launch_bounds__(256) void transpose_w(const float* __restrict__ W,
                                                   u16* __restrict__ Wt) {
  __shared__ u16 tile[64][65];
  int bn = blockIdx.x & 63;
  int bk = blockIdx.x >> 6;
  int n0 = bn * 64, k0 = bk * 64;
  for (int i = threadIdx.x; i < 4096; i += 256) {
    int r = i >> 6, c = i & 63;
    tile[c][r] = f2bf(W[(size_t)(k0 + r) * G_ + n0 + c]);
  }
  __syncthreads();
  for (int i = threadIdx.x; i < 4096; i += 256) {
    int r = i >> 6, c = i & 63;
    Wt[(size_t)(n0 + r) * K2_ + k0 + c] = tile[r][c];
  }
}

// xg[(t*B+b)*D + d] = bf16(emb[inputs[b][t]][d])
__global__ __launch_bounds__(256) void gather_x(const int* __restrict__ inputs,
                                                const float* __restrict__ emb,
                                                u16* __restrict__ xg) {
  int idx = blockIdx.x * 256 + threadIdx.x;
  int d4 = idx & 255;
  int tb = idx >> 8;
  int t = tb >> 6, b = tb & 63;
  int tok = inputs[b * T_ + t];
  float4 v = ((const float4*)(emb + (size_t)tok * D_))[d4];
  unsigned long long pk = (unsigned long long)f2bf(v.x)
                        | ((unsigned long long)f2bf(v.y) << 16)
                        | ((unsigned long long)f2bf(v.z) << 32)
                        | ((unsigned long long)f2bf(v.w) << 48);
  *(unsigned long long*)(xg + (size_t)tb * D_ + d4 * 4) = pk;
}

__global__ void zero_buf(uint4* p, int n) {
  int i = blockIdx.x * blockDim.x + threadIdx.x;
  if (i < n) p[i] = make_uint4(0u, 0u, 0u, 0u);
}

// Persistent pipelined 2-layer LSTM.
// 256 blocks x 512 threads, 1 block/CU. Blocks [0,128): layer 1 (t = i);
// blocks [128,256): layer 2 (t = i-1). One grid barrier per iteration.
// Block owns rows [rg*32, rg*32+32) x gate-cols {g*1024 + cg*16 + dc}.
// Wave wv owns k-slice [wv*256, wv*256+256): weights in 128 VGPRs/lane.
__global__ __launch_bounds__(512, 2) void lstm_persist(
    const u16* __restrict__ wt1, const u16* __restrict__ wt2,
    const u16* __restrict__ xg,
    u16* __restrict__ h1n, u16* __restrict__ h1buf, u16* __restrict__ h2buf,
    const float* __restrict__ b1, const float* __restrict__ b2,
    const int* __restrict__ lens, float* __restrict__ out,
    int* cnt) {
  __shared__ __attribute__((aligned(16))) float part[8][64][36];
  __shared__ __attribute__((aligned(16))) float gsum[64][36];
  const int blk = blockIdx.x;
  const int L = blk >> 7;
  const int lb = blk & 127;
  const int rg = lb & 1;
  const int cg = lb >> 1;
  const int tid = threadIdx.x;
  const int lane = tid & 63;
  const int wv = tid >> 6;
  const int dc = lane & 15;
  const int kq = lane >> 4;

  const u16* wt = L ? wt2 : wt1;
  const float* bias = L ? b2 : b1;

  // register-resident weights: 4 gates x 8 k-steps of bf16x8
  bf16x8 wreg[4][8];
  {
    const u16* wb = wt + (size_t)(cg * 16 + dc) * K2_ + wv * 256 + kq * 8;
    #pragma unroll
    for (int g = 0; g < 4; ++g) {
      #pragma unroll
      for (int ks = 0; ks < 8; ++ks)
        wreg[g][ks] = *(const bf16x8*)(wb + (size_t)g * D_ * K2_ + ks * 32);
    }
  }

  // cell-role constants (thread -> one (row, dcol) element)
  const int crow = tid >> 4;          // 0..31
  const int cdc = tid & 15;
  const int grow = rg * 32 + crow;    // global batch row
  const int dcol = cg * 16 + cdc;     // global d column
  const int len_r = lens[grow];
  float bias_g[4];
  #pragma unroll
  for (int g = 0; g < 4; ++g) bias_g[g] = bias[g * D_ + dcol];
  float creg = 0.f, hreg = 0.f, outreg = 0.f;

  const int r0 = rg * 32 + (lane & 15);       // rt=0 A-row
  const int koff = (wv & 3) * 256 + kq * 8;   // k within the 1024-wide half

  for (int i = 0; i <= 128; ++i) {
    const bool active = L ? (i >= 1) : (i < 128);
    const int t = L ? i - 1 : i;
    if (active) {
      const u16* src;
      if (L == 0)
        src = (wv < 4) ? xg + (size_t)t * (B_ * D_)
                       : h1buf + (size_t)((i + 3) & 3) * (B_ * D_);
      else
        src = (wv < 4) ? h1n + (size_t)((i + 3) & 3) * (B_ * D_)
                       : h2buf + (size_t)((i + 2) & 3) * (B_ * D_);
      const u16* a0p = src + (size_t)r0 * D_ + koff;

      f32x4 acc[2][4];
      #pragma unroll
      for (int rt = 0; rt < 2; ++rt)
        #pragma unroll
        for (int g = 0; g < 4; ++g)
          acc[rt][g] = (f32x4){0.f, 0.f, 0.f, 0.f};

      #pragma unroll
      for (int ks = 0; ks < 8; ++ks) {
        bf16x8 a0 = *(const bf16x8*)(a0p + ks * 32);
        bf16x8 a1 = *(const bf16x8*)(a0p + 16 * D_ + ks * 32);
        #pragma unroll
        for (int g = 0; g < 4; ++g) {
          acc[0][g] = __builtin_amdgcn_mfma_f32_16x16x32_bf16(a0, wreg[g][ks], acc[0][g], 0, 0, 0);
          acc[1][g] = __builtin_amdgcn_mfma_f32_16x16x32_bf16(a1, wreg[g][ks], acc[1][g], 0, 0, 0);
        }
      }

      // partials to LDS: D-layout col = lane&15, row = kq*4 + r
      #pragma unroll
      for (int rt = 0; rt < 2; ++rt)
        #pragma unroll
        for (int g = 0; g < 4; ++g)
          *(f32x4*)&part[wv][g * 16 + dc][rt * 16 + kq * 4] = acc[rt][g];
      __syncthreads();

      // 8-way k-reduction: thread -> (col = tid>>3, rows (tid&7)*4..+3)
      {
        const int rcol = tid >> 3;
        const int rrow = (tid & 7) * 4;
        f32x4 s = *(const f32x4*)&part[0][rcol][rrow];
        #pragma unroll
        for (int w = 1; w < 8; ++w) s += *(const f32x4*)&part[w][rcol][rrow];
        *(f32x4*)&gsum[rcol][rrow] = s;
      }
      __syncthreads();

      // fused LSTM cell, one element per thread
      {
        float gi = gsum[cdc][crow] + bias_g[0];
        float gj = gsum[16 + cdc][crow] + bias_g[1];
        float gf = gsum[32 + cdc][crow] + bias_g[2];
        float go = gsum[48 + cdc][crow] + bias_g[3];
        float is = 1.f / (1.f + expf(-gi));
        float fs = 1.f / (1.f + expf(-gf));
        float os = 1.f / (1.f + expf(-go));
        float jt = tanhf(gj);
        float c_new = creg * fs + is * jt;
        float h_new = tanhf(c_new) * os;
        bool m = t < len_r;
        if (m) { creg = c_new; hreg = h_new; }
        size_t soff = (size_t)grow * D_ + dcol;
        if (L == 0) {
          h1n[(size_t)(i & 3) * (B_ * D_) + soff] = f2bf(h_new);   // raw h1n feeds layer 2
          h1buf[(size_t)(i & 3) * (B_ * D_) + soff] = f2bf(hreg);  // masked state
        } else {
          h2buf[(size_t)((i + 3) & 3) * (B_ * D_) + soff] = f2bf(hreg);
          if (m) outreg += h_new;
        }
      }
    }
    if (i < 128) {
      __syncthreads();
      if (tid == 0) {
        __threadfence();
        __hip_atomic_fetch_add(&cnt[i], 1, __ATOMIC_ACQ_REL, __HIP_MEMORY_SCOPE_AGENT);
        while (__hip_atomic_load(&cnt[i], __ATOMIC_ACQUIRE, __HIP_MEMORY_SCOPE_AGENT) < 256)
          __builtin_amdgcn_s_sleep(2);
      }
      __syncthreads();
    }
  }
  if (L == 1) out[(size_t)grow * D_ + dcol] = outreg;
}

extern "C" void kernel_launch(void* const* d_in, const int* in_sizes, int n_in,
                              void* d_out, int out_size, void* d_ws, size_t ws_size,
                              hipStream_t stream) {
  const int* inputs  = (const int*)d_in[0];
  const int* lengths = (const int*)d_in[1];
  const float* emb   = (const float*)d_in[2];
  const float* W1    = (const float*)d_in[3];
  const float* b1    = (const float*)d_in[4];
  const float* W2    = (const float*)d_in[5];
  const float* b2    = (const float*)d_in[6];
  float* out = (float*)d_out;

  // workspace carve (~49.5 MiB)
  char* p = (char*)d_ws;
  u16* wt1   = (u16*)p; p += (size_t)G_ * K2_ * 2;        // 16 MiB
  u16* wt2   = (u16*)p; p += (size_t)G_ * K2_ * 2;        // 16 MiB
  u16* xg    = (u16*)p; p += (size_t)T_ * B_ * D_ * 2;    // 16 MiB
  u16* h1n   = (u16*)p; p += (size_t)4 * B_ * D_ * 2;     // 512 KiB (x4 ring)
  u16* h1buf = (u16*)p; p += (size_t)4 * B_ * D_ * 2;     // 512 KiB
  u16* h2buf = (u16*)p; p += (size_t)4 * B_ * D_ * 2;     // 512 KiB
  int* cnt   = (int*)p; p += 512;                          // 128 barrier counters

  hipLaunchKernelGGL(transpose_w, dim3(2048), dim3(256), 0, stream, W1, wt1);
  hipLaunchKernelGGL(transpose_w, dim3(2048), dim3(256), 0, stream, W2, wt2);
  hipLaunchKernelGGL(gather_x, dim3(8192), dim3(256), 0, stream, inputs, emb, xg);
  // zero h1n+h1buf+h2buf+cnt contiguously: (3*524288 + 512)/16 = 98336 uint4
  hipLaunchKernelGGL(zero_buf, dim3(385), dim3(256), 0, stream, (uint4*)h1n, 98336);

  hipLaunchKernelGGL(lstm_persist, dim3(256), dim3(512), 0, stream,
                     wt1, wt2, xg, h1n, h1buf, h2buf, b1, b2, lengths, out, cnt);
}

// Round 3
// 1772.529 us; speedup vs baseline: 4.4781x; 1.8807x over previous
//
#include <hip/hip_runtime.h>

#define B_ 64
#define T_ 128
#define D_ 1024
#define K2_ 2048
#define G_ 4096

typedef __attribute__((ext_vector_type(8))) short bf16x8;
typedef __attribute__((ext_vector_type(4))) float f32x4;
typedef unsigned short u16;

__device__ __forceinline__ u16 f2bf(float f) {
  unsigned int u = __float_as_uint(f);
  u += 0x7FFF + ((u >> 16) & 1);   // round-to-nearest-even
  return (u16)(u >> 16);
}

__device__ __forceinline__ float fast_sigmoid(float x) {
  return 1.f / (1.f + __expf(-x));
}
__device__ __forceinline__ float fast_tanh(float x) {
  float e = __expf(-2.f * fabsf(x));
  float t = (1.f - e) / (1.f + e);
  return copysignf(t, x);
}

// Wt[n][k] = bf16(W[k][n]);  W:[2048][4096] f32, Wt:[4096][2048] bf16
__global__ __launch_bounds__(256) void transpose_w(const float* __restrict__ W,
                                                   u16* __restrict__ Wt) {
  __shared__ u16 tile[64][65];
  int bn = blockIdx.x & 63;
  int bk = blockIdx.x >> 6;
  int n0 = bn * 64, k0 = bk * 64;
  for (int i = threadIdx.x; i < 4096; i += 256) {
    int r = i >> 6, c = i & 63;
    tile[c][r] = f2bf(W[(size_t)(k0 + r) * G_ + n0 + c]);
  }
  __syncthreads();
  for (int i = threadIdx.x; i < 4096; i += 256) {
    int r = i >> 6, c = i & 63;
    Wt[(size_t)(n0 + r) * K2_ + k0 + c] = tile[r][c];
  }
}

// xg[(t*B+b)*D + d] = bf16(emb[inputs[b][t]][d])
__global__ __launch_bounds__(256) void gather_x(const int* __restrict__ inputs,
                                                const float* __restrict__ emb,
                                                u16* __restrict__ xg) {
  int idx = blockIdx.x * 256 + threadIdx.x;
  int d4 = idx & 255;
  int tb = idx >> 8;
  int t = tb >> 6, b = tb & 63;
  int tok = inputs[b * T_ + t];
  float4 v = ((const float4*)(emb + (size_t)tok * D_))[d4];
  unsigned long long pk = (unsigned long long)f2bf(v.x)
                        | ((unsigned long long)f2bf(v.y) << 16)
                        | ((unsigned long long)f2bf(v.z) << 32)
                        | ((unsigned long long)f2bf(v.w) << 48);
  *(unsigned long long*)(xg + (size_t)tb * D_ + d4 * 4) = pk;
}

__global__ void zero_buf(uint4* p, int n) {
  int i = blockIdx.x * blockDim.x + threadIdx.x;
  if (i < n) p[i] = make_uint4(0u, 0u, 0u, 0u);
}

// Hierarchical grid barrier: 8 padded group counters (same-XCD under
// round-robin dispatch) -> 1 root -> 1 release flag. One release fence
// (wbL2) on arrival, one acquire fence (inv) on exit, per block per iter.
__device__ __forceinline__ void grid_barrier(int* gcnt, int* root, int* rel,
                                             int i, int blk, int tid) {
  __syncthreads();
  if (tid == 0) {
    __builtin_amdgcn_fence(__ATOMIC_RELEASE, "agent");
    int* gc = gcnt + (i * 8 + (blk & 7)) * 32;
    int a = __hip_atomic_fetch_add(gc, 1, __ATOMIC_RELAXED, __HIP_MEMORY_SCOPE_AGENT);
    if (a == 31) {
      int r = __hip_atomic_fetch_add(root + i * 32, 1, __ATOMIC_RELAXED, __HIP_MEMORY_SCOPE_AGENT);
      if (r == 7)
        __hip_atomic_store(rel + i * 32, 1, __ATOMIC_RELAXED, __HIP_MEMORY_SCOPE_AGENT);
    }
    while (__hip_atomic_load(rel + i * 32, __ATOMIC_RELAXED, __HIP_MEMORY_SCOPE_AGENT) == 0)
      __builtin_amdgcn_s_sleep(1);
    __builtin_amdgcn_fence(__ATOMIC_ACQUIRE, "agent");
  }
  __syncthreads();
}

// Persistent pipelined 2-layer LSTM. 256 blocks x 512 threads, 1 block/CU.
// Blocks [0,128): layer 1 (t=i); [128,256): layer 2 (t=i-1).
__global__ __launch_bounds__(512, 2) void lstm_persist(
    const u16* __restrict__ wt1, const u16* __restrict__ wt2,
    const u16* __restrict__ xg,
    u16* __restrict__ h1n, u16* __restrict__ h1buf, u16* __restrict__ h2buf,
    const float* __restrict__ b1, const float* __restrict__ b2,
    const int* __restrict__ lens, float* __restrict__ out,
    int* gcnt, int* root, int* rel) {
  __shared__ __attribute__((aligned(16))) float part[8][64][36];
  __shared__ __attribute__((aligned(16))) float gsum[64][36];
  const int blk = blockIdx.x;
  const int L = blk >> 7;
  const int lb = blk & 127;
  const int rg = lb & 1;
  const int cg = lb >> 1;
  const int tid = threadIdx.x;
  const int lane = tid & 63;
  const int wv = tid >> 6;
  const int dc = lane & 15;
  const int kq = lane >> 4;

  const u16* wt = L ? wt2 : wt1;
  const float* bias = L ? b2 : b1;

  // register-resident weights: 4 gates x 8 k-steps of bf16x8 = 128 VGPRs
  bf16x8 wreg[4][8];
  {
    const u16* wb = wt + (size_t)(cg * 16 + dc) * K2_ + wv * 256 + kq * 8;
    #pragma unroll
    for (int g = 0; g < 4; ++g)
      #pragma unroll
      for (int ks = 0; ks < 8; ++ks)
        wreg[g][ks] = *(const bf16x8*)(wb + (size_t)g * D_ * K2_ + ks * 32);
  }
  // Opaque materialization: compiler can no longer re-load these inside the
  // loop (the barrier's fences would otherwise force per-iteration reloads).
  #pragma unroll
  for (int g = 0; g < 4; ++g)
    #pragma unroll
    for (int ks = 0; ks < 8; ++ks)
      asm volatile("" : "+v"(wreg[g][ks]));

  const int crow = tid >> 4;          // 0..31
  const int cdc = tid & 15;
  const int grow = rg * 32 + crow;
  const int dcol = cg * 16 + cdc;
  const int len_r = lens[grow];
  float bias_g[4];
  #pragma unroll
  for (int g = 0; g < 4; ++g) bias_g[g] = bias[g * D_ + dcol];
  float creg = 0.f, hreg = 0.f, outreg = 0.f;

  const int r0 = rg * 32 + (lane & 15);
  const int koff = (wv & 3) * 256 + kq * 8;

  for (int i = 0; i <= 128; ++i) {
    const bool active = L ? (i >= 1) : (i < 128);
    const int t = L ? i - 1 : i;
    if (active) {
      const u16* src;
      if (L == 0)
        src = (wv < 4) ? xg + (size_t)t * (B_ * D_)
                       : h1buf + (size_t)((i + 3) & 3) * (B_ * D_);
      else
        src = (wv < 4) ? h1n + (size_t)((i + 3) & 3) * (B_ * D_)
                       : h2buf + (size_t)((i + 2) & 3) * (B_ * D_);
      const u16* a0p = src + (size_t)r0 * D_ + koff;

      f32x4 acc[2][4];
      #pragma unroll
      for (int rt = 0; rt < 2; ++rt)
        #pragma unroll
        for (int g = 0; g < 4; ++g)
          acc[rt][g] = (f32x4){0.f, 0.f, 0.f, 0.f};

      #pragma unroll
      for (int ks = 0; ks < 8; ++ks) {
        bf16x8 a0 = *(const bf16x8*)(a0p + ks * 32);
        bf16x8 a1 = *(const bf16x8*)(a0p + 16 * D_ + ks * 32);
        #pragma unroll
        for (int g = 0; g < 4; ++g) {
          acc[0][g] = __builtin_amdgcn_mfma_f32_16x16x32_bf16(a0, wreg[g][ks], acc[0][g], 0, 0, 0);
          acc[1][g] = __builtin_amdgcn_mfma_f32_16x16x32_bf16(a1, wreg[g][ks], acc[1][g], 0, 0, 0);
        }
      }

      // partials to LDS: D-layout col = lane&15, row = kq*4 + r
      #pragma unroll
      for (int rt = 0; rt < 2; ++rt)
        #pragma unroll
        for (int g = 0; g < 4; ++g)
          *(f32x4*)&part[wv][g * 16 + dc][rt * 16 + kq * 4] = acc[rt][g];
      __syncthreads();

      // 8-way k-reduction
      {
        const int rcol = tid >> 3;
        const int rrow = (tid & 7) * 4;
        f32x4 s = *(const f32x4*)&part[0][rcol][rrow];
        #pragma unroll
        for (int w = 1; w < 8; ++w) s += *(const f32x4*)&part[w][rcol][rrow];
        *(f32x4*)&gsum[rcol][rrow] = s;
      }
      __syncthreads();

      // fused LSTM cell, one element per thread
      {
        float gi = gsum[cdc][crow] + bias_g[0];
        float gj = gsum[16 + cdc][crow] + bias_g[1];
        float gf = gsum[32 + cdc][crow] + bias_g[2];
        float go = gsum[48 + cdc][crow] + bias_g[3];
        float is = fast_sigmoid(gi);
        float fs = fast_sigmoid(gf);
        float os = fast_sigmoid(go);
        float jt = fast_tanh(gj);
        float c_new = creg * fs + is * jt;
        float h_new = fast_tanh(c_new) * os;
        bool m = t < len_r;
        if (m) { creg = c_new; hreg = h_new; }
        size_t soff = (size_t)grow * D_ + dcol;
        if (L == 0) {
          h1n[(size_t)(i & 3) * (B_ * D_) + soff] = f2bf(h_new);   // raw h1n -> layer 2
          h1buf[(size_t)(i & 3) * (B_ * D_) + soff] = f2bf(hreg);  // masked state
        } else {
          h2buf[(size_t)((i + 3) & 3) * (B_ * D_) + soff] = f2bf(hreg);
          if (m) outreg += h_new;
        }
      }
    }
    if (i < 128) grid_barrier(gcnt, root, rel, i, blk, tid);
  }
  if (L == 1) out[(size_t)grow * D_ + dcol] = outreg;
}

extern "C" void kernel_launch(void* const* d_in, const int* in_sizes, int n_in,
                              void* d_out, int out_size, void* d_ws, size_t ws_size,
                              hipStream_t stream) {
  const int* inputs  = (const int*)d_in[0];
  const int* lengths = (const int*)d_in[1];
  const float* emb   = (const float*)d_in[2];
  const float* W1    = (const float*)d_in[3];
  const float* b1    = (const float*)d_in[4];
  const float* W2    = (const float*)d_in[5];
  const float* b2    = (const float*)d_in[6];
  float* out = (float*)d_out;

  // workspace carve (~49.7 MiB)
  char* p = (char*)d_ws;
  u16* wt1   = (u16*)p; p += (size_t)G_ * K2_ * 2;        // 16 MiB
  u16* wt2   = (u16*)p; p += (size_t)G_ * K2_ * 2;        // 16 MiB
  u16* xg    = (u16*)p; p += (size_t)T_ * B_ * D_ * 2;    // 16 MiB
  u16* h1n   = (u16*)p; p += (size_t)4 * B_ * D_ * 2;     // 512 KiB ring
  u16* h1buf = (u16*)p; p += (size_t)4 * B_ * D_ * 2;     // 512 KiB ring
  u16* h2buf = (u16*)p; p += (size_t)4 * B_ * D_ * 2;     // 512 KiB ring
  int* gcnt  = (int*)p; p += 128 * 8 * 32 * 4;            // 128 KiB (padded lines)
  int* root  = (int*)p; p += 128 * 32 * 4;                // 16 KiB
  int* rel   = (int*)p; p += 128 * 32 * 4;                // 16 KiB

  hipLaunchKernelGGL(transpose_w, dim3(2048), dim3(256), 0, stream, W1, wt1);
  hipLaunchKernelGGL(transpose_w, dim3(2048), dim3(256), 0, stream, W2, wt2);
  hipLaunchKernelGGL(gather_x, dim3(8192), dim3(256), 0, stream, inputs, emb, xg);
  // zero rings + barrier counters contiguously:
  // 3*524288 + 131072 + 16384 + 16384 = 1,736,704 B = 108,544 uint4
  hipLaunchKernelGGL(zero_buf, dim3(425), dim3(256), 0, stream, (uint4*)h1n, 108544);

  hipLaunchKernelGGL(lstm_persist, dim3(256), dim3(512), 0, stream,
                     wt1, wt2, xg, h1n, h1buf, h2buf, b1, b2, lengths, out,
                     gcnt, root, rel);
}

// Round 4
// 1316.550 us; speedup vs baseline: 6.0291x; 1.3463x over previous
//
#include <hip/hip_runtime.h>

#define B_ 64
#define T_ 128
#define D_ 1024
#define K2_ 2048
#define G_ 4096

typedef __attribute__((ext_vector_type(8))) short bf16x8;
typedef __attribute__((ext_vector_type(4))) float f32x4;
typedef unsigned short u16;
typedef unsigned long long u64;

__device__ __forceinline__ u16 f2bf(float f) {
  unsigned int u = __float_as_uint(f);
  u += 0x7FFF + ((u >> 16) & 1);   // round-to-nearest-even
  return (u16)(u >> 16);
}

__device__ __forceinline__ float fast_sigmoid(float x) {
  return 1.f / (1.f + __expf(-x));
}
__device__ __forceinline__ float fast_tanh(float x) {
  float e = __expf(-2.f * fabsf(x));
  float t = (1.f - e) / (1.f + e);
  return copysignf(t, x);
}

// Coherent (cross-XCD) 16B load as two agent-scope relaxed atomic u64 loads:
// compiles to global_load_dwordx2 sc0 sc1 (L1+L2 bypass, served at IF).
__device__ __forceinline__ bf16x8 load_coh16(const u16* p) {
  union { u64 q[2]; bf16x8 v; } u;
  u.q[0] = __hip_atomic_load((u64*)p,       __ATOMIC_RELAXED, __HIP_MEMORY_SCOPE_AGENT);
  u.q[1] = __hip_atomic_load((u64*)(p + 4), __ATOMIC_RELAXED, __HIP_MEMORY_SCOPE_AGENT);
  return u.v;
}

// Pair-pack two adjacent bf16 (tid even = low half) and store 4B coherent.
__device__ __forceinline__ void store_pair_coh(u16* base, size_t soff, u16 v, int tid) {
  unsigned other = __shfl_xor((unsigned)v, 1);
  if (!(tid & 1))
    __hip_atomic_store((unsigned*)(base + soff), (unsigned)v | (other << 16),
                       __ATOMIC_RELAXED, __HIP_MEMORY_SCOPE_AGENT);
}

// Wt[n][k] = bf16(W[k][n]);  W:[2048][4096] f32, Wt:[4096][2048] bf16
__global__ __launch_bounds__(256) void transpose_w(const float* __restrict__ W,
                                                   u16* __restrict__ Wt) {
  __shared__ u16 tile[64][65];
  int bn = blockIdx.x & 63;
  int bk = blockIdx.x >> 6;
  int n0 = bn * 64, k0 = bk * 64;
  for (int i = threadIdx.x; i < 4096; i += 256) {
    int r = i >> 6, c = i & 63;
    tile[c][r] = f2bf(W[(size_t)(k0 + r) * G_ + n0 + c]);
  }
  __syncthreads();
  for (int i = threadIdx.x; i < 4096; i += 256) {
    int r = i >> 6, c = i & 63;
    Wt[(size_t)(n0 + r) * K2_ + k0 + c] = tile[r][c];
  }
}

// xg[(t*B+b)*D + d] = bf16(emb[inputs[b][t]][d])
__global__ __launch_bounds__(256) void gather_x(const int* __restrict__ inputs,
                                                const float* __restrict__ emb,
                                                u16* __restrict__ xg) {
  int idx = blockIdx.x * 256 + threadIdx.x;
  int d4 = idx & 255;
  int tb = idx >> 8;
  int t = tb >> 6, b = tb & 63;
  int tok = inputs[b * T_ + t];
  float4 v = ((const float4*)(emb + (size_t)tok * D_))[d4];
  u64 pk = (u64)f2bf(v.x)
         | ((u64)f2bf(v.y) << 16)
         | ((u64)f2bf(v.z) << 32)
         | ((u64)f2bf(v.w) << 48);
  *(u64*)(xg + (size_t)tb * D_ + d4 * 4) = pk;
}

__global__ void zero_buf(uint4* p, int n) {
  int i = blockIdx.x * blockDim.x + threadIdx.x;
  if (i < n) p[i] = make_uint4(0u, 0u, 0u, 0u);
}

template<bool COH>
__device__ __forceinline__ void gemm_half(const u16* a0p, const bf16x8 (&wreg)[4][8],
                                          f32x4 (&acc)[2][4]) {
  #pragma unroll
  for (int ks = 0; ks < 8; ++ks) {
    bf16x8 a0, a1;
    if (COH) {
      a0 = load_coh16(a0p + ks * 32);
      a1 = load_coh16(a0p + 16 * D_ + ks * 32);
    } else {
      a0 = *(const bf16x8*)(a0p + ks * 32);
      a1 = *(const bf16x8*)(a0p + 16 * D_ + ks * 32);
    }
    #pragma unroll
    for (int g = 0; g < 4; ++g) {
      acc[0][g] = __builtin_amdgcn_mfma_f32_16x16x32_bf16(a0, wreg[g][ks], acc[0][g], 0, 0, 0);
      acc[1][g] = __builtin_amdgcn_mfma_f32_16x16x32_bf16(a1, wreg[g][ks], acc[1][g], 0, 0, 0);
    }
  }
}

// Persistent pipelined 2-layer LSTM. 256 blocks x 512 threads, 1 block/CU.
// Blocks [0,128): layer 1 (t=i); [128,256): layer 2 (t=i-1).
// Fence-free coherence: h-rings via sc0/sc1 (agent-relaxed atomics);
// weights/xg stay warm in L1/L2. Per-layer hierarchical barriers.
__global__ __launch_bounds__(512, 2) void lstm_persist(
    const u16* __restrict__ wt1, const u16* __restrict__ wt2,
    const u16* __restrict__ xg,
    u16* __restrict__ h1n, u16* __restrict__ h1buf, u16* __restrict__ h2buf,
    const float* __restrict__ b1, const float* __restrict__ b2,
    const int* __restrict__ lens, float* __restrict__ out,
    int* cnt, int* root, int* done) {
  __shared__ __attribute__((aligned(16))) float part[8][64][36];
  __shared__ __attribute__((aligned(16))) float gsum[64][36];
  const int blk = blockIdx.x;
  const int L = blk >> 7;
  const int lb = blk & 127;
  const int rg = lb & 1;
  const int cg = lb >> 1;
  const int tid = threadIdx.x;
  const int lane = tid & 63;
  const int wv = tid >> 6;
  const int dc = lane & 15;
  const int kq = lane >> 4;

  const u16* wt = L ? wt2 : wt1;
  const float* bias = L ? b2 : b1;

  // register-resident weights: 4 gates x 8 k-steps of bf16x8 = 128 VGPRs
  bf16x8 wreg[4][8];
  {
    const u16* wb = wt + (size_t)(cg * 16 + dc) * K2_ + wv * 256 + kq * 8;
    #pragma unroll
    for (int g = 0; g < 4; ++g)
      #pragma unroll
      for (int ks = 0; ks < 8; ++ks)
        wreg[g][ks] = *(const bf16x8*)(wb + (size_t)g * D_ * K2_ + ks * 32);
  }
  #pragma unroll
  for (int g = 0; g < 4; ++g)
    #pragma unroll
    for (int ks = 0; ks < 8; ++ks)
      asm volatile("" : "+v"(wreg[g][ks]));   // pin: forbid re-load inside loop

  const int crow = tid >> 4;          // 0..31
  const int cdc = tid & 15;
  const int grow = rg * 32 + crow;
  const int dcol = cg * 16 + cdc;
  const int len_r = lens[grow];
  float bias_g[4];
  #pragma unroll
  for (int g = 0; g < 4; ++g) bias_g[g] = bias[g * D_ + dcol];
  float creg = 0.f, hreg = 0.f, outreg = 0.f;

  const int r0 = rg * 32 + (lane & 15);
  const int koff = (wv & 3) * 256 + kq * 8;

  for (int i = 0; i <= 128; ++i) {
    const bool active = L ? (i >= 1) : (i < 128);
    const int t = L ? i - 1 : i;
    if (active) {
      f32x4 acc[2][4];
      #pragma unroll
      for (int rt = 0; rt < 2; ++rt)
        #pragma unroll
        for (int g = 0; g < 4; ++g)
          acc[rt][g] = (f32x4){0.f, 0.f, 0.f, 0.f};

      if (L == 0 && wv < 4) {
        const u16* a0p = xg + (size_t)t * (B_ * D_) + (size_t)r0 * D_ + koff;
        gemm_half<false>(a0p, wreg, acc);
      } else {
        const u16* src;
        if (L == 0)
          src = h1buf + (size_t)((i + 3) & 3) * (B_ * D_);
        else
          src = (wv < 4) ? h1n + (size_t)((i + 3) & 3) * (B_ * D_)
                         : h2buf + (size_t)((i + 2) & 3) * (B_ * D_);
        gemm_half<true>(src + (size_t)r0 * D_ + koff, wreg, acc);
      }

      // partials to LDS: D-layout col = lane&15, row = kq*4 + r
      #pragma unroll
      for (int rt = 0; rt < 2; ++rt)
        #pragma unroll
        for (int g = 0; g < 4; ++g)
          *(f32x4*)&part[wv][g * 16 + dc][rt * 16 + kq * 4] = acc[rt][g];
      __syncthreads();

      // 8-way k-reduction
      {
        const int rcol = tid >> 3;
        const int rrow = (tid & 7) * 4;
        f32x4 s = *(const f32x4*)&part[0][rcol][rrow];
        #pragma unroll
        for (int w = 1; w < 8; ++w) s += *(const f32x4*)&part[w][rcol][rrow];
        *(f32x4*)&gsum[rcol][rrow] = s;
      }
      __syncthreads();

      // fused LSTM cell, one element per thread
      {
        float gi = gsum[cdc][crow] + bias_g[0];
        float gj = gsum[16 + cdc][crow] + bias_g[1];
        float gf = gsum[32 + cdc][crow] + bias_g[2];
        float go = gsum[48 + cdc][crow] + bias_g[3];
        float is = fast_sigmoid(gi);
        float fs = fast_sigmoid(gf);
        float os = fast_sigmoid(go);
        float jt = fast_tanh(gj);
        float c_new = creg * fs + is * jt;
        float h_new = fast_tanh(c_new) * os;
        bool m = t < len_r;
        if (m) { creg = c_new; hreg = h_new; }
        size_t soff = (size_t)grow * D_ + dcol;
        if (L == 0) {
          store_pair_coh(h1n  + (size_t)(i & 3) * (B_ * D_), soff, f2bf(h_new), tid);
          store_pair_coh(h1buf + (size_t)(i & 3) * (B_ * D_), soff, f2bf(hreg), tid);
        } else {
          store_pair_coh(h2buf + (size_t)((i + 3) & 3) * (B_ * D_), soff, f2bf(hreg), tid);
          if (m) outreg += h_new;
        }
      }
    }

    if (i < 128) {
      // per-layer hierarchical barrier (8 same-XCD groups of 16 -> root of 8).
      // __syncthreads drains vmcnt(0) per wave, so all sc1 stores are at the
      // coherence point before tid0 signals arrival. No fences anywhere.
      __syncthreads();
      if (tid == 0) {
        int li = L * 128 + i;
        int* gc = cnt + (size_t)(li * 8 + (lb & 7)) * 32;
        int a = __hip_atomic_fetch_add(gc, 1, __ATOMIC_RELAXED, __HIP_MEMORY_SCOPE_AGENT);
        if (a == 15) {
          int r = __hip_atomic_fetch_add(root + (size_t)li * 32, 1,
                                         __ATOMIC_RELAXED, __HIP_MEMORY_SCOPE_AGENT);
          if (r == 7)
            __hip_atomic_store(done + (size_t)li * 32, 1,
                               __ATOMIC_RELAXED, __HIP_MEMORY_SCOPE_AGENT);
        }
        // own-layer sync
        while (!__hip_atomic_load(done + (size_t)li * 32,
                                  __ATOMIC_RELAXED, __HIP_MEMORY_SCOPE_AGENT))
          __builtin_amdgcn_s_sleep(1);
        if (L == 1) {
          // L2 starting iter i+1 reads h1n[i&3] written by L1 iter i
          while (!__hip_atomic_load(done + (size_t)i * 32,
                                    __ATOMIC_RELAXED, __HIP_MEMORY_SCOPE_AGENT))
            __builtin_amdgcn_s_sleep(1);
        } else if (i >= 2) {
          // L1 starting iter i+1 rewrites slot (i+1)&3, last read by L2 iter i-2
          while (!__hip_atomic_load(done + (size_t)(128 + i - 2) * 32,
                                    __ATOMIC_RELAXED, __HIP_MEMORY_SCOPE_AGENT))
            __builtin_amdgcn_s_sleep(1);
        }
      }
      __syncthreads();
    }
  }
  if (L == 1) out[(size_t)grow * D_ + dcol] = outreg;
}

extern "C" void kernel_launch(void* const* d_in, const int* in_sizes, int n_in,
                              void* d_out, int out_size, void* d_ws, size_t ws_size,
                              hipStream_t stream) {
  const int* inputs  = (const int*)d_in[0];
  const int* lengths = (const int*)d_in[1];
  const float* emb   = (const float*)d_in[2];
  const float* W1    = (const float*)d_in[3];
  const float* b1    = (const float*)d_in[4];
  const float* W2    = (const float*)d_in[5];
  const float* b2    = (const float*)d_in[6];
  float* out = (float*)d_out;

  // workspace carve (~49.9 MiB)
  char* p = (char*)d_ws;
  u16* wt1   = (u16*)p; p += (size_t)G_ * K2_ * 2;        // 16 MiB
  u16* wt2   = (u16*)p; p += (size_t)G_ * K2_ * 2;        // 16 MiB
  u16* xg    = (u16*)p; p += (size_t)T_ * B_ * D_ * 2;    // 16 MiB
  u16* h1n   = (u16*)p; p += (size_t)4 * B_ * D_ * 2;     // 512 KiB ring
  u16* h1buf = (u16*)p; p += (size_t)4 * B_ * D_ * 2;     // 512 KiB ring
  u16* h2buf = (u16*)p; p += (size_t)4 * B_ * D_ * 2;     // 512 KiB ring
  int* cnt   = (int*)p; p += (size_t)2 * 128 * 8 * 32 * 4; // 256 KiB
  int* root  = (int*)p; p += (size_t)2 * 128 * 32 * 4;     // 32 KiB
  int* done  = (int*)p; p += (size_t)2 * 128 * 32 * 4;     // 32 KiB

  hipLaunchKernelGGL(transpose_w, dim3(2048), dim3(256), 0, stream, W1, wt1);
  hipLaunchKernelGGL(transpose_w, dim3(2048), dim3(256), 0, stream, W2, wt2);
  hipLaunchKernelGGL(gather_x, dim3(8192), dim3(256), 0, stream, inputs, emb, xg);
  // zero rings + barrier state contiguously:
  // 3*524288 + 262144 + 32768 + 32768 = 1,900,544 B = 118,784 uint4
  hipLaunchKernelGGL(zero_buf, dim3(464), dim3(256), 0, stream, (uint4*)h1n, 118784);

  hipLaunchKernelGGL(lstm_persist, dim3(256), dim3(512), 0, stream,
                     wt1, wt2, xg, h1n, h1buf, h2buf, b1, b2, lengths, out,
                     cnt, root, done);
}